// Round 7
// baseline (2167.595 us; speedup 1.0000x reference)
//
#include <hip/hip_runtime.h>

// B=64,K=64 -> 4096 (b,k) blocks; L=128 rows; D=128; H=256; 6 layers.
// 1024-thread blocks (16 waves): 4 waves/SIMD for latency hiding (R6 was 2).
// Phase-1 fp32 tiles XOR-swizzled on 16B chunks: chunk' = chunk ^ (row&31)
#define FID4(r,c4) ((r)*128 + ((((c4) ^ ((r)&31))) << 2))               // float4 chunk addr (dwords)
#define FIDS(r,c)  ((r)*128 + (((((c)>>2) ^ ((r)&31))) << 2) + ((c)&3))  // scalar float addr
// Phase-2 fp16 x-buffer [128][256], swizzled on 8-elem (16B) chunks
#define XIDX(r,c)  ((r)*256 + (((((c)>>3) ^ ((r)&7))) << 3) + ((c)&7))

typedef _Float16 half_t;
typedef __attribute__((ext_vector_type(8))) _Float16 f16x8;
typedef __attribute__((ext_vector_type(4))) float f32x4;

__device__ __forceinline__ float tanh_fast(float x){
    float e = __expf(2.0f * x);
    return 1.0f - 2.0f / (e + 1.0f);
}

// 8 fp32 -> f16x8 (RNE)
__device__ __forceinline__ f16x8 cvt8(float4 a, float4 b){
    f16x8 r;
    r[0]=(half_t)a.x; r[1]=(half_t)a.y; r[2]=(half_t)a.z; r[3]=(half_t)a.w;
    r[4]=(half_t)b.x; r[5]=(half_t)b.y; r[6]=(half_t)b.z; r[7]=(half_t)b.w;
    return r;
}

// Single kernel, no workspace (R5 tripwire lesson: no inter-kernel d_ws hand-off).
__global__ __launch_bounds__(1024, 4)   // 16 waves = 4/EU -> 128-VGPR budget
void fused_mlp_som(const float* __restrict__ ctx_in,   // (4096, 2, 128, 128) f32
                   const float* __restrict__ Ws,       // (6,256,256) f32
                   const float* __restrict__ bs,       // (6,256)
                   const float* __restrict__ Wout,     // (256)
                   const float* __restrict__ bout,     // (1)
                   float* __restrict__ out)            // (4096)
{
    extern __shared__ char smem[];
    float* ctxS   = (float*)smem;                 // [128][128] f32, swizzled (64 KB)
    float* entS   = ctxS + 128*128;               // [128][128] f32, swizzled (64 KB)
    float* inv_cn = entS + 128*128;               // [128]
    float* inv_en = inv_cn + 128;                 // [128]
    int*   idxm   = (int*)(inv_en + 128);         // [128]
    float* redbuf = (float*)(idxm + 128);         // [16]
    // Phase-2 alias (after barrier): fp16 x-buffer [128][256] = 64 KB over ctxS
    half_t* xf = (half_t*)smem;

    const int tid  = threadIdx.x;
    const int lane = tid & 63;
    const int bk   = blockIdx.x;

    // ---------------- stage ctx/ent -> LDS (swizzled float4 writes) ----------------
    const float4* gbase = (const float4*)(ctx_in + (size_t)bk * (2*128*128));
    #pragma unroll
    for (int it = 0; it < 4; ++it){
        int fi = tid + 1024*it;          // 0..4095 float4s per 64KB tile
        int r  = fi >> 5;
        int c4 = fi & 31;
        float4 v = gbase[fi];
        *(float4*)&ctxS[FID4(r,c4)] = v;
        float4 e = gbase[fi + 4096];
        *(float4*)&entS[FID4(r,c4)] = e;
    }
    __syncthreads();

    // ---------------- row norms: threads 0-511 ONLY, bit-identical serial order ----------------
    if (tid < 512){
        int hf = tid & 1;
        int r  = (tid >> 1) & 127;
        const float* tile = (tid < 256) ? ctxS : entS;
        float s = 0.f;
        #pragma unroll
        for (int u = 0; u < 16; ++u){
            float4 v = *(const float4*)&tile[FID4(r, 16*hf + u)];
            s = fmaf(v.x, v.x, s); s = fmaf(v.y, v.y, s);
            s = fmaf(v.z, v.z, s); s = fmaf(v.w, v.w, s);
        }
        s += __shfl_xor(s, 1);
        if (hf == 0){
            float inv = 1.0f / sqrtf(s);
            if (tid < 256) inv_cn[r] = inv; else inv_en[r] = inv;
        }
    }
    __syncthreads();

    // ---------------- similarity (fp32 VALU, bit-identical per-acc order) + argmax ----------------
    // 1024 threads: thread (ti,tj) ti in [0,32): rows 4ti..4ti+3, cols {tj,+32,+64,+96}
    {
        const int ti = tid >> 5;
        const int tj = tid & 31;
        const int l0 = ti * 4;
        float acc[4][4];
        #pragma unroll
        for (int i = 0; i < 4; ++i)
            #pragma unroll
            for (int j = 0; j < 4; ++j) acc[i][j] = 0.f;

        for (int kc = 0; kc < 32; ++kc){
            float4 e0 = *(const float4*)&entS[FID4(tj     , kc)];
            float4 e1 = *(const float4*)&entS[FID4(tj + 32, kc)];
            float4 e2 = *(const float4*)&entS[FID4(tj + 64, kc)];
            float4 e3 = *(const float4*)&entS[FID4(tj + 96, kc)];
            #pragma unroll
            for (int i = 0; i < 4; ++i){
                float4 a = *(const float4*)&ctxS[FID4(l0+i, kc)];
                acc[i][0] = fmaf(a.x,e0.x,acc[i][0]); acc[i][0] = fmaf(a.y,e0.y,acc[i][0]);
                acc[i][0] = fmaf(a.z,e0.z,acc[i][0]); acc[i][0] = fmaf(a.w,e0.w,acc[i][0]);
                acc[i][1] = fmaf(a.x,e1.x,acc[i][1]); acc[i][1] = fmaf(a.y,e1.y,acc[i][1]);
                acc[i][1] = fmaf(a.z,e1.z,acc[i][1]); acc[i][1] = fmaf(a.w,e1.w,acc[i][1]);
                acc[i][2] = fmaf(a.x,e2.x,acc[i][2]); acc[i][2] = fmaf(a.y,e2.y,acc[i][2]);
                acc[i][2] = fmaf(a.z,e2.z,acc[i][2]); acc[i][2] = fmaf(a.w,e2.w,acc[i][2]);
                acc[i][3] = fmaf(a.x,e3.x,acc[i][3]); acc[i][3] = fmaf(a.y,e3.y,acc[i][3]);
                acc[i][3] = fmaf(a.w,e3.w,acc[i][3]); acc[i][3] = fmaf(a.z,e3.z,acc[i][3]);
            }
        }
        #pragma unroll
        for (int i = 0; i < 4; ++i){
            float best = -1e38f; int bi = 0;
            #pragma unroll
            for (int j = 0; j < 4; ++j){
                int m = tj + 32*j;
                float v = acc[i][j] * inv_en[m];
                if (v > best || (v == best && m < bi)){ best = v; bi = m; }
            }
            #pragma unroll
            for (int s = 1; s < 32; s <<= 1){
                float ov = __shfl_xor(best, s);
                int   oi = __shfl_xor(bi,   s);
                if (ov > best || (ov == best && oi < bi)){ best = ov; bi = oi; }
            }
            if (tj == 0) idxm[l0 + i] = bi;
        }
    }
    __syncthreads();

    // ---------------- build x0 = [ctx_n | ent_n[idx]] as fp16, XOR-swizzled ----------------
    {
        const int c  = tid & 255;
        const int hb = tid >> 8;         // 0..3
        half_t pk[32];
        #pragma unroll
        for (int r = 0; r < 32; ++r){
            int l = hb*32 + r;
            float v;
            if (c < 128){
                v = ctxS[FIDS(l, c)] * inv_cn[l];
            } else {
                int mi = idxm[l];
                v = entS[FIDS(mi, c-128)] * inv_en[mi];
            }
            pk[r] = (half_t)v;
        }
        __syncthreads();
        #pragma unroll
        for (int r = 0; r < 32; ++r){
            int l = hb*32 + r;
            xf[XIDX(l, c)] = pk[r];
        }
    }
    __syncthreads();

    // ---------------- 6-layer MLP: fp16 single-product MFMA, 2M x 8N wave grid ----------------
    // wave (wm, wn): rows 64wm..64wm+63 (mt 0..3), cols [32wn, 32wn+32)
    const int wv    = tid >> 6;          // 0..15
    const int wm    = wv >> 3;           // 0..1
    const int wn    = wv & 7;            // 0..7
    const int lan15 = lane & 15;
    const int lq    = lane >> 4;
    const int n0    = 32*wn + lan15;
    const int n1    = n0 + 16;
    const int bno0  = n0 * 256;
    const int bno1  = n1 * 256;
    const int kb    = 8*lq;
    const int aBase = (64*wm + lan15) * 256;   // + mt*4096 + aoff

    // raw fp32 W prefetch state, carried across layers (converted to fp16 at use)
    float4 p0a = *(const float4*)&Ws[bno0 + kb];
    float4 p0b = *(const float4*)&Ws[bno0 + kb + 4];
    float4 p1a = *(const float4*)&Ws[bno1 + kb];
    float4 p1b = *(const float4*)&Ws[bno1 + kb + 4];

    #pragma unroll 1
    for (int layer = 0; layer < 6; ++layer){
        const float* WsL = Ws + layer*65536;
        const float* WsN = Ws + ((layer < 5) ? (layer+1) : 5)*65536;

        f32x4 acc[4][2];
        #pragma unroll
        for (int mt = 0; mt < 4; ++mt){
            acc[mt][0] = (f32x4){0.f,0.f,0.f,0.f};
            acc[mt][1] = (f32x4){0.f,0.f,0.f,0.f};
        }

        #pragma unroll 1
        for (int ks = 0; ks < 8; ++ks){
            // batched A-frag reads: one vaddr + 4 imm offsets (mt*4096 halfs = 8192 B)
            const int aoff = (((4*ks + lq) ^ (lan15 & 7)) << 3);
            f16x8 a[4];
            #pragma unroll
            for (int mt = 0; mt < 4; ++mt)
                a[mt] = *(const f16x8*)&xf[aBase + mt*4096 + aoff];
            // convert this ks's B frags from the prefetched fp32
            f16x8 b0 = cvt8(p0a, p0b);
            f16x8 b1 = cvt8(p1a, p1b);
            // prefetch next ks (at ks==7: next layer's first frags) — raw fp32
            const float* pW = (ks < 7) ? WsL : WsN;
            const int kn = (ks < 7) ? (32*(ks+1) + kb) : kb;
            p0a = *(const float4*)&pW[bno0 + kn];
            p0b = *(const float4*)&pW[bno0 + kn + 4];
            p1a = *(const float4*)&pW[bno1 + kn];
            p1b = *(const float4*)&pW[bno1 + kn + 4];
            #pragma unroll
            for (int mt = 0; mt < 4; ++mt){
                acc[mt][0] = __builtin_amdgcn_mfma_f32_16x16x32_f16(a[mt], b0, acc[mt][0], 0,0,0);
                acc[mt][1] = __builtin_amdgcn_mfma_f32_16x16x32_f16(a[mt], b1, acc[mt][1], 0,0,0);
            }
        }
        __syncthreads();   // all waves done reading xf (next-layer W loads stay in flight)

        if (layer < 5){
            float bias0 = bs[layer*256 + n0];
            float bias1 = bs[layer*256 + n1];
            #pragma unroll
            for (int mt = 0; mt < 4; ++mt){
                #pragma unroll
                for (int r = 0; r < 4; ++r){
                    int row = 64*wm + 16*mt + 4*lq + r;   // C/D: col=lane&15, row=(lane>>4)*4+reg
                    xf[XIDX(row, n0)] = (half_t)tanh_fast(acc[mt][0][r] + bias0);
                    xf[XIDX(row, n1)] = (half_t)tanh_fast(acc[mt][1][r] + bias1);
                }
            }
            __syncthreads();
        } else {
            float bias0 = bs[5*256 + n0];
            float bias1 = bs[5*256 + n1];
            float w0 = Wout[n0];
            float w1 = Wout[n1];
            float part = 0.f;
            #pragma unroll
            for (int mt = 0; mt < 4; ++mt){
                #pragma unroll
                for (int r = 0; r < 4; ++r){
                    part = fmaf(tanh_fast(acc[mt][0][r] + bias0), w0, part);
                    part = fmaf(tanh_fast(acc[mt][1][r] + bias1), w1, part);
                }
            }
            #pragma unroll
            for (int s = 1; s < 64; s <<= 1) part += __shfl_xor(part, s);
            if (lane == 0) redbuf[wv] = part;
            __syncthreads();
            if (tid == 0){
                float s = 0.f;
                #pragma unroll
                for (int i = 0; i < 16; ++i) s += redbuf[i];
                out[bk] = s + 128.0f * bout[0];
            }
        }
    }
}

extern "C" void kernel_launch(void* const* d_in, const int* in_sizes, int n_in,
                              void* d_out, int out_size, void* d_ws, size_t ws_size,
                              hipStream_t stream)
{
    (void)in_sizes; (void)n_in; (void)out_size; (void)d_ws; (void)ws_size;
    const float* ctx  = (const float*)d_in[0];
    const float* Ws   = (const float*)d_in[1];
    const float* bs   = (const float*)d_in[2];
    const float* Wout = (const float*)d_in[3];
    const float* bout = (const float*)d_in[4];
    float* out = (float*)d_out;

    const int smem_bytes = 2*128*128*4 + 128*4 + 128*4 + 128*4 + 16*4;  // 132672 B
    hipFuncSetAttribute(reinterpret_cast<const void*>(fused_mlp_som),
                        hipFuncAttributeMaxDynamicSharedMemorySize, smem_bytes);
    fused_mlp_som<<<dim3(4096), dim3(1024), smem_bytes, stream>>>(ctx, Ws, bs, Wout, bout, out);
}

// Round 8
// 2058.535 us; speedup vs baseline: 1.0530x; 1.0530x over previous
//
#include <hip/hip_runtime.h>

// B=64,K=64 -> 4096 (b,k) blocks; L=128 rows; D=128; H=256; 6 layers.
// 256-thread blocks, 64KB LDS -> TWO workgroups co-resident per CU (phase overlap).
// ctx in LDS (fp32, swizzled); ent stays in global (L1/L2-hot), read bit-identically.
#define FID4(r,c4) ((r)*128 + ((((c4) ^ ((r)&31))) << 2))               // float4 chunk addr (dwords)
#define FIDS(r,c)  ((r)*128 + (((((c)>>2) ^ ((r)&31))) << 2) + ((c)&3))  // scalar float addr
// fp16 x-buffer [128][256] aliasing ctxS row-for-row (512B rows), swizzled on 16B chunks
#define XIDX(r,c)  ((r)*256 + (((((c)>>3) ^ ((r)&7))) << 3) + ((c)&7))

typedef _Float16 half_t;
typedef __attribute__((ext_vector_type(8))) _Float16 f16x8;
typedef __attribute__((ext_vector_type(4))) float f32x4;

__device__ __forceinline__ float tanh_fast(float x){
    float e = __expf(2.0f * x);
    return 1.0f - 2.0f / (e + 1.0f);
}

// 8 fp32 -> f16x8 (RNE)
__device__ __forceinline__ f16x8 cvt8(float4 a, float4 b){
    f16x8 r;
    r[0]=(half_t)a.x; r[1]=(half_t)a.y; r[2]=(half_t)a.z; r[3]=(half_t)a.w;
    r[4]=(half_t)b.x; r[5]=(half_t)b.y; r[6]=(half_t)b.z; r[7]=(half_t)b.w;
    return r;
}

__global__ __launch_bounds__(256, 2)   // 2 waves/EU min -> 256-reg budget; LDS allows 2 WGs/CU
void fused_mlp_som(const float* __restrict__ ctx_in,   // (4096, 2, 128, 128) f32
                   const float* __restrict__ Ws,       // (6,256,256)
                   const float* __restrict__ bs,       // (6,256)
                   const float* __restrict__ Wout,     // (256)
                   const float* __restrict__ bout,     // (1)
                   float* __restrict__ out)            // (4096)
{
    extern __shared__ char smem[];
    float* ctxS   = (float*)smem;                 // [128][128] f32, swizzled (64 KB)
    float* inv_cn = ctxS + 128*128;               // [128]
    float* inv_en = inv_cn + 128;                 // [128]
    int*   idxm   = (int*)(inv_en + 128);         // [128]
    float* redbuf = (float*)(idxm + 128);         // [4]
    half_t* xf = (half_t*)smem;                   // alias over ctxS: [128][256] fp16 (row r over ctx row r)

    const int tid  = threadIdx.x;
    const int lane = tid & 63;
    const int bk   = blockIdx.x;

    const float* gctx = ctx_in + (size_t)bk * 32768;
    const float* gent = gctx + 16384;

    // ---------------- stage ctx -> LDS (swizzled float4 writes); ent NOT staged ----------------
    {
        const float4* gb = (const float4*)gctx;
        #pragma unroll
        for (int it = 0; it < 16; ++it){
            int fi = tid + 256*it;           // 0..4095 float4s (64KB)
            int r  = fi >> 5;
            int c4 = fi & 31;
            *(float4*)&ctxS[FID4(r,c4)] = gb[fi];
        }
    }
    __syncthreads();

    // ---------------- row norms: ctx from LDS, ent from global (both bit-identical chains) ----------------
    {
        int hf = tid & 1;
        int r  = tid >> 1;                   // 0..127
        float s = 0.f, t = 0.f;
        #pragma unroll
        for (int u = 0; u < 16; ++u){
            float4 v = *(const float4*)&ctxS[FID4(r, 16*hf + u)];
            s = fmaf(v.x, v.x, s); s = fmaf(v.y, v.y, s);
            s = fmaf(v.z, v.z, s); s = fmaf(v.w, v.w, s);
        }
        #pragma unroll
        for (int u = 0; u < 16; ++u){
            float4 v = *(const float4*)&gent[r*128 + 64*hf + 4*u];   // same elements/order as staged path
            t = fmaf(v.x, v.x, t); t = fmaf(v.y, v.y, t);
            t = fmaf(v.z, v.z, t); t = fmaf(v.w, v.w, t);
        }
        s += __shfl_xor(s, 1);
        t += __shfl_xor(t, 1);
        if (hf == 0){
            inv_cn[r] = 1.0f / sqrtf(s);
            inv_en[r] = 1.0f / sqrtf(t);
        }
    }
    __syncthreads();

    // ---------------- similarity (fp32, canonical R1-R4 chain order) + argmax ----------------
    // 256 threads: thread (ti,tj), ti in [0,8): rows 16ti..16ti+15; cols {tj,+32,+64,+96}
    // ent rows read from GLOBAL (L1-hot, one-kc-ahead double buffer); ctx rows from LDS.
    {
        const int ti = tid >> 5;
        const int tj = tid & 31;
        const int l0 = ti * 16;
        float acc[16][4];
        #pragma unroll
        for (int i = 0; i < 16; ++i)
            #pragma unroll
            for (int j = 0; j < 4; ++j) acc[i][j] = 0.f;

        float4 e0 = *(const float4*)&gent[(tj      )*128];
        float4 e1 = *(const float4*)&gent[(tj + 32 )*128];
        float4 e2 = *(const float4*)&gent[(tj + 64 )*128];
        float4 e3 = *(const float4*)&gent[(tj + 96 )*128];
        for (int kc = 0; kc < 32; ++kc){
            const int kn = ((kc+1)&31) << 2;
            float4 f0 = *(const float4*)&gent[(tj      )*128 + kn];
            float4 f1 = *(const float4*)&gent[(tj + 32 )*128 + kn];
            float4 f2 = *(const float4*)&gent[(tj + 64 )*128 + kn];
            float4 f3 = *(const float4*)&gent[(tj + 96 )*128 + kn];
            #pragma unroll
            for (int i = 0; i < 16; ++i){
                float4 a = *(const float4*)&ctxS[FID4(l0+i, kc)];
                acc[i][0] = fmaf(a.x,e0.x,acc[i][0]); acc[i][0] = fmaf(a.y,e0.y,acc[i][0]);
                acc[i][0] = fmaf(a.z,e0.z,acc[i][0]); acc[i][0] = fmaf(a.w,e0.w,acc[i][0]);
                acc[i][1] = fmaf(a.x,e1.x,acc[i][1]); acc[i][1] = fmaf(a.y,e1.y,acc[i][1]);
                acc[i][1] = fmaf(a.z,e1.z,acc[i][1]); acc[i][1] = fmaf(a.w,e1.w,acc[i][1]);
                acc[i][2] = fmaf(a.x,e2.x,acc[i][2]); acc[i][2] = fmaf(a.y,e2.y,acc[i][2]);
                acc[i][2] = fmaf(a.z,e2.z,acc[i][2]); acc[i][2] = fmaf(a.w,e2.w,acc[i][2]);
                acc[i][3] = fmaf(a.x,e3.x,acc[i][3]); acc[i][3] = fmaf(a.y,e3.y,acc[i][3]);
                acc[i][3] = fmaf(a.z,e3.z,acc[i][3]); acc[i][3] = fmaf(a.w,e3.w,acc[i][3]);
            }
            e0=f0; e1=f1; e2=f2; e3=f3;
        }
        #pragma unroll
        for (int i = 0; i < 16; ++i){
            float best = -1e38f; int bi = 0;
            #pragma unroll
            for (int j = 0; j < 4; ++j){
                int m = tj + 32*j;
                float v = acc[i][j] * inv_en[m];
                if (v > best || (v == best && m < bi)){ best = v; bi = m; }
            }
            #pragma unroll
            for (int s = 1; s < 32; s <<= 1){
                float ov = __shfl_xor(best, s);
                int   oi = __shfl_xor(bi,   s);
                if (ov > best || (ov == best && oi < bi)){ best = ov; bi = oi; }
            }
            if (tj == 0) idxm[l0 + i] = bi;
        }
    }
    __syncthreads();

    // ---------------- build x0 = [ctx_n | ent_n[idx]] fp16 over ctxS, 2 chunks of 64 rows ----------------
    // xf row r occupies exactly ctx row r's 512B -> writing rows [0,64) only clobbers already-read rows.
    {
        const int c = tid;                   // 0..255; waves are branch-uniform (c<128 = waves 0-1)
        #pragma unroll 1
        for (int hb = 0; hb < 2; ++hb){
            half_t pk[64];
            #pragma unroll
            for (int r = 0; r < 64; ++r){
                int l = hb*64 + r;
                float v;
                if (c < 128){
                    v = ctxS[FIDS(l, c)] * inv_cn[l];
                } else {
                    int mi = idxm[l];
                    v = gent[mi*128 + (c-128)] * inv_en[mi];
                }
                pk[r] = (half_t)v;
            }
            __syncthreads();
            #pragma unroll
            for (int r = 0; r < 64; ++r){
                int l = hb*64 + r;
                xf[XIDX(l, c)] = pk[r];
            }
            __syncthreads();
        }
    }

    // ---------------- 6-layer MLP: fp16 single-product MFMA, 4 waves N-split ----------------
    // wave wv owns cols [64wv, 64wv+64) (4 nf-frags); a[8] shared across 4 B-frags -> 32 MFMA / 8 ds_read.
    const int wv    = tid >> 6;              // 0..3
    const int lan15 = lane & 15;
    const int lq    = lane >> 4;
    const int kb    = 8*lq;
    const int aBase = lan15*256;

    // raw fp32 W prefetch (4 cols x 8 k), carried across layers
    float4 pA[4], pB[4];
    #pragma unroll
    for (int nf = 0; nf < 4; ++nf){
        int bn = (64*wv + 16*nf + lan15)*256;
        pA[nf] = *(const float4*)&Ws[bn + kb];
        pB[nf] = *(const float4*)&Ws[bn + kb + 4];
    }

    #pragma unroll 1
    for (int layer = 0; layer < 6; ++layer){
        const float* WsL = Ws + layer*65536;
        const float* WsN = Ws + ((layer < 5) ? (layer+1) : 5)*65536;

        f32x4 acc[8][4];
        #pragma unroll
        for (int mt = 0; mt < 8; ++mt)
            #pragma unroll
            for (int nf = 0; nf < 4; ++nf)
                acc[mt][nf] = (f32x4){0.f,0.f,0.f,0.f};

        #pragma unroll 1
        for (int ks = 0; ks < 8; ++ks){
            const int aoff = (((4*ks + lq) ^ (lan15 & 7)) << 3);
            f16x8 a[8];
            #pragma unroll
            for (int mt = 0; mt < 8; ++mt)
                a[mt] = *(const f16x8*)&xf[aBase + mt*4096 + aoff];
            f16x8 b[4];
            #pragma unroll
            for (int nf = 0; nf < 4; ++nf) b[nf] = cvt8(pA[nf], pB[nf]);
            // prefetch next ks (at ks==7: next layer's first frags)
            const float* pW = (ks < 7) ? WsL : WsN;
            const int kn = (ks < 7) ? (32*(ks+1) + kb) : kb;
            #pragma unroll
            for (int nf = 0; nf < 4; ++nf){
                int bn = (64*wv + 16*nf + lan15)*256;
                pA[nf] = *(const float4*)&pW[bn + kn];
                pB[nf] = *(const float4*)&pW[bn + kn + 4];
            }
            #pragma unroll
            for (int mt = 0; mt < 8; ++mt)
                #pragma unroll
                for (int nf = 0; nf < 4; ++nf)
                    acc[mt][nf] = __builtin_amdgcn_mfma_f32_16x16x32_f16(a[mt], b[nf], acc[mt][nf], 0,0,0);
        }
        __syncthreads();   // all waves done reading xf (next-layer W loads stay in flight)

        if (layer < 5){
            float bias[4];
            #pragma unroll
            for (int nf = 0; nf < 4; ++nf) bias[nf] = bs[layer*256 + 64*wv + 16*nf + lan15];
            #pragma unroll
            for (int mt = 0; mt < 8; ++mt){
                #pragma unroll
                for (int nf = 0; nf < 4; ++nf){
                    const int n = 64*wv + 16*nf + lan15;
                    #pragma unroll
                    for (int r = 0; r < 4; ++r){
                        int row = 16*mt + 4*lq + r;   // C/D: col=lane&15, row=(lane>>4)*4+reg
                        xf[XIDX(row, n)] = (half_t)tanh_fast(acc[mt][nf][r] + bias[nf]);
                    }
                }
            }
            __syncthreads();
        } else {
            float bias[4], w[4];
            #pragma unroll
            for (int nf = 0; nf < 4; ++nf){
                const int n = 64*wv + 16*nf + lan15;
                bias[nf] = bs[5*256 + n];
                w[nf]    = Wout[n];
            }
            float part = 0.f;
            #pragma unroll
            for (int mt = 0; mt < 8; ++mt)
                #pragma unroll
                for (int nf = 0; nf < 4; ++nf)
                    #pragma unroll
                    for (int r = 0; r < 4; ++r)
                        part = fmaf(tanh_fast(acc[mt][nf][r] + bias[nf]), w[nf], part);
            #pragma unroll
            for (int s = 1; s < 64; s <<= 1) part += __shfl_xor(part, s);
            if (lane == 0) redbuf[wv] = part;
            __syncthreads();
            if (tid == 0){
                float s = redbuf[0] + redbuf[1] + redbuf[2] + redbuf[3];
                out[bk] = s + 128.0f * bout[0];
            }
        }
    }
}

extern "C" void kernel_launch(void* const* d_in, const int* in_sizes, int n_in,
                              void* d_out, int out_size, void* d_ws, size_t ws_size,
                              hipStream_t stream)
{
    (void)in_sizes; (void)n_in; (void)out_size; (void)d_ws; (void)ws_size;
    const float* ctx  = (const float*)d_in[0];
    const float* Ws   = (const float*)d_in[1];
    const float* bs   = (const float*)d_in[2];
    const float* Wout = (const float*)d_in[3];
    const float* bout = (const float*)d_in[4];
    float* out = (float*)d_out;

    const int smem_bytes = 128*128*4 + 128*4 + 128*4 + 128*4 + 4*4;  // 67088 B -> 2 WGs/CU
    hipFuncSetAttribute(reinterpret_cast<const void*>(fused_mlp_som),
                        hipFuncAttributeMaxDynamicSharedMemorySize, smem_bytes);
    fused_mlp_som<<<dim3(4096), dim3(256), smem_bytes, stream>>>(ctx, Ws, bs, Wout, bout, out);
}

// Round 10
// 1535.021 us; speedup vs baseline: 1.4121x; 1.3410x over previous
//
#include <hip/hip_runtime.h>

// B=64,K=64 -> 4096 (b,k) blocks; L=128 rows; D=128; H=256; 6 layers.
// 256-thread WGs, ~65.5 KB LDS -> 2 WGs/CU (phase overlap between independent blocks).
// Sim reads ONLY LDS (k-split staged halves); x0 re-reads global once (L2-hot).
// [128][64] f32 half-tile, float4-chunk addr (dwords), 4-bit XOR swizzle:
#define HID4(r,c4) ((r)*64 + ((((c4) ^ ((r)&15))) << 2))
// fp16 x-buffer [128][256] over the two half-tiles, swizzled on 8-elem (16B) chunks:
#define XIDX(r,c)  ((r)*256 + (((((c)>>3) ^ ((r)&7))) << 3) + ((c)&7))

typedef _Float16 half_t;
typedef __attribute__((ext_vector_type(8))) _Float16 f16x8;
typedef __attribute__((ext_vector_type(4))) _Float16 f16x4;
typedef __attribute__((ext_vector_type(4))) float f32x4;

__device__ __forceinline__ float tanh_fast(float x){
    float e = __expf(2.0f * x);
    return 1.0f - 2.0f / (e + 1.0f);
}

// 8 fp32 -> f16x8 (RNE)
__device__ __forceinline__ f16x8 cvt8(float4 a, float4 b){
    f16x8 r;
    r[0]=(half_t)a.x; r[1]=(half_t)a.y; r[2]=(half_t)a.z; r[3]=(half_t)a.w;
    r[4]=(half_t)b.x; r[5]=(half_t)b.y; r[6]=(half_t)b.z; r[7]=(half_t)b.w;
    return r;
}

__global__ __launch_bounds__(256, 2)   // 4-wave WGs; 2 co-resident WGs/CU = 2 waves/EU -> 256-reg budget
void fused_mlp_som(const float* __restrict__ ctx_in,   // (4096, 2, 128, 128) f32
                   const float* __restrict__ Ws,       // (6,256,256)
                   const float* __restrict__ bs,       // (6,256)
                   const float* __restrict__ Wout,     // (256)
                   const float* __restrict__ bout,     // (1)
                   float* __restrict__ out)            // (4096)
{
    extern __shared__ char smem[];
    float* S0     = (float*)smem;                 // [128][64] ctx k-half (32 KB)
    float* S1     = S0 + 128*64;                  // [128][64] ent k-half (32 KB)
    float* inv_cn = S1 + 128*64;                  // [128]
    float* inv_en = inv_cn + 128;                 // [128]
    int*   idxm   = (int*)(inv_en + 128);         // [128]
    float* redbuf = (float*)(idxm + 128);         // [4]
    half_t* xf    = (half_t*)smem;                // [128][256] fp16 over S0+S1 (64 KB), live after sim

    const int tid  = threadIdx.x;
    const int lane = tid & 63;
    const int bk   = blockIdx.x;

    const float*  gctx = ctx_in + (size_t)bk * 32768;
    const float*  gent = gctx + 16384;
    const float4* gc4  = (const float4*)gctx;     // [128][32] float4
    const float4* ge4  = (const float4*)gent;

    // norms: thread (nr, hf); each (nr,hf) 16-chunk chain lives entirely in k-half hf
    const int hf = tid & 1;
    const int nr = tid >> 1;
    float ns = 0.f, nt = 0.f;

    // sim: thread (ti,tj): rows 16ti..16ti+15, cols {tj,+32,+64,+96}
    const int ti = tid >> 5;
    const int tj = tid & 31;
    const int l0 = ti * 16;
    float acc[16][4];
    #pragma unroll
    for (int i = 0; i < 16; ++i)
        #pragma unroll
        for (int j = 0; j < 4; ++j) acc[i][j] = 0.f;

    #pragma unroll 1
    for (int h = 0; h < 2; ++h){
        if (h) __syncthreads();          // all phase-0 readers done before restage
        // ---- stage k-half h: ctx cols 64h..64h+63 -> S0, ent -> S1 ----
        #pragma unroll
        for (int it = 0; it < 8; ++it){
            int fi = tid + 256*it;       // 0..2047 -> (r, c4) over 128x16 chunks
            int r  = fi >> 4;
            int c4 = fi & 15;
            *(float4*)&S0[HID4(r,c4)] = gc4[r*32 + 16*h + c4];
            *(float4*)&S1[HID4(r,c4)] = ge4[r*32 + 16*h + c4];
        }
        __syncthreads();
        // ---- norm partials for this half (chain order preserved) ----
        if (hf == h){
            #pragma unroll
            for (int u = 0; u < 16; ++u){
                float4 v = *(const float4*)&S0[HID4(nr, u)];
                ns = fmaf(v.x, v.x, ns); ns = fmaf(v.y, v.y, ns);
                ns = fmaf(v.z, v.z, ns); ns = fmaf(v.w, v.w, ns);
                float4 w = *(const float4*)&S1[HID4(nr, u)];
                nt = fmaf(w.x, w.x, nt); nt = fmaf(w.y, w.y, nt);
                nt = fmaf(w.z, w.z, nt); nt = fmaf(w.w, w.w, nt);
            }
        }
        // ---- sim accumulate kc = 16h .. 16h+15 (canonical chain order) ----
        for (int kk = 0; kk < 16; ++kk){
            float4 e0 = *(const float4*)&S1[HID4(tj     , kk)];
            float4 e1 = *(const float4*)&S1[HID4(tj + 32, kk)];
            float4 e2 = *(const float4*)&S1[HID4(tj + 64, kk)];
            float4 e3 = *(const float4*)&S1[HID4(tj + 96, kk)];
            #pragma unroll
            for (int i = 0; i < 16; ++i){
                float4 a = *(const float4*)&S0[HID4(l0+i, kk)];
                acc[i][0] = fmaf(a.x,e0.x,acc[i][0]); acc[i][0] = fmaf(a.y,e0.y,acc[i][0]);
                acc[i][0] = fmaf(a.z,e0.z,acc[i][0]); acc[i][0] = fmaf(a.w,e0.w,acc[i][0]);
                acc[i][1] = fmaf(a.x,e1.x,acc[i][1]); acc[i][1] = fmaf(a.y,e1.y,acc[i][1]);
                acc[i][1] = fmaf(a.z,e1.z,acc[i][1]); acc[i][1] = fmaf(a.w,e1.w,acc[i][1]);
                acc[i][2] = fmaf(a.x,e2.x,acc[i][2]); acc[i][2] = fmaf(a.y,e2.y,acc[i][2]);
                acc[i][2] = fmaf(a.z,e2.z,acc[i][2]); acc[i][2] = fmaf(a.w,e2.w,acc[i][2]);
                acc[i][3] = fmaf(a.x,e3.x,acc[i][3]); acc[i][3] = fmaf(a.y,e3.y,acc[i][3]);
                acc[i][3] = fmaf(a.z,e3.z,acc[i][3]); acc[i][3] = fmaf(a.w,e3.w,acc[i][3]);
            }
        }
    }

    // ---- combine norms, publish ----
    ns += __shfl_xor(ns, 1);
    nt += __shfl_xor(nt, 1);
    if (hf == 0){
        inv_cn[nr] = 1.0f / sqrtf(ns);
        inv_en[nr] = 1.0f / sqrtf(nt);
    }
    __syncthreads();

    // ---- argmax (canonical compare + butterfly) ----
    #pragma unroll
    for (int i = 0; i < 16; ++i){
        float best = -1e38f; int bi = 0;
        #pragma unroll
        for (int j = 0; j < 4; ++j){
            int m = tj + 32*j;
            float v = acc[i][j] * inv_en[m];
            if (v > best || (v == best && m < bi)){ best = v; bi = m; }
        }
        #pragma unroll
        for (int s = 1; s < 32; s <<= 1){
            float ov = __shfl_xor(best, s);
            int   oi = __shfl_xor(bi,   s);
            if (ov > best || (ov == best && oi < bi)){ best = ov; bi = oi; }
        }
        if (tj == 0) idxm[l0 + i] = bi;
    }
    __syncthreads();

    // ---- x0 = [ctx_n | ent_n[idx]] fp16 over S0+S1, from GLOBAL (L2-hot, row-vectorized) ----
    {
        const int l   = tid >> 1;
        const int sel = tid & 1;
        const float4* src;
        float sc;
        int col0;
        if (sel == 0){ src = (const float4*)(gctx + l*128);          sc = inv_cn[l];  col0 = 0;   }
        else         { int mi = idxm[l]; src = (const float4*)(gent + mi*128); sc = inv_en[mi]; col0 = 128; }
        #pragma unroll
        for (int u = 0; u < 32; ++u){
            float4 v = src[u];
            f16x4 hv;
            hv[0] = (half_t)(v.x * sc); hv[1] = (half_t)(v.y * sc);
            hv[2] = (half_t)(v.z * sc); hv[3] = (half_t)(v.w * sc);
            int c = col0 + 4*u;
            *(f16x4*)&xf[l*256 + ((((c>>3) ^ (l&7))) << 3) + (c&7)] = hv;
        }
    }
    __syncthreads();

    // ---- 6-layer MLP: fp16 single-product MFMA, 4 waves N-split-4 (FULL column coverage) ----
    // wave wv: ALL 128 rows (mt 0..7, two a[4] batches) x cols [64wv, 64wv+64) (nf 0..3).
    // mac[8][4] = 128 accs/thread (structural minimum for 256 threads); no W reg-prefetch,
    // no a[8] batch -> peak live ~185 regs < 256 (R8's spill fixed by shrinking non-acc set).
    const int wv    = tid >> 6;              // 0..3
    const int lan15 = lane & 15;
    const int lq    = lane >> 4;
    const int kb    = 8*lq;
    const int ncb   = 64*wv;
    const int aBase = lan15*256;             // + mt*4096 + aoff

    #pragma unroll 1
    for (int layer = 0; layer < 6; ++layer){
        const float* WsL = Ws + layer*65536;

        f32x4 mac[8][4];
        #pragma unroll
        for (int mt = 0; mt < 8; ++mt)
            #pragma unroll
            for (int nf = 0; nf < 4; ++nf)
                mac[mt][nf] = (f32x4){0.f,0.f,0.f,0.f};

        #pragma unroll 1
        for (int ks = 0; ks < 8; ++ks){
            const int aoff = (((4*ks + lq) ^ (lan15 & 7)) << 3);
            // W for this ks: load fp32 (L2-hot), cvt to fp16 (latency covered by 2nd WG + sibling wave)
            f16x8 b[4];
            #pragma unroll
            for (int nf = 0; nf < 4; ++nf){
                const int bn = (ncb + 16*nf + lan15)*256 + 32*ks + kb;
                float4 qa = *(const float4*)&WsL[bn];
                float4 qb = *(const float4*)&WsL[bn + 4];
                b[nf] = cvt8(qa, qb);
            }
            // batch 1: rows 0..63 (mt 0..3)
            {
                f16x8 a[4];
                #pragma unroll
                for (int mt = 0; mt < 4; ++mt)
                    a[mt] = *(const f16x8*)&xf[aBase + mt*4096 + aoff];
                #pragma unroll
                for (int mt = 0; mt < 4; ++mt)
                    #pragma unroll
                    for (int nf = 0; nf < 4; ++nf)
                        mac[mt][nf] = __builtin_amdgcn_mfma_f32_16x16x32_f16(a[mt], b[nf], mac[mt][nf], 0,0,0);
            }
            // batch 2: rows 64..127 (mt 4..7)
            {
                f16x8 a[4];
                #pragma unroll
                for (int mt = 0; mt < 4; ++mt)
                    a[mt] = *(const f16x8*)&xf[aBase + (mt+4)*4096 + aoff];
                #pragma unroll
                for (int mt = 0; mt < 4; ++mt)
                    #pragma unroll
                    for (int nf = 0; nf < 4; ++nf)
                        mac[mt+4][nf] = __builtin_amdgcn_mfma_f32_16x16x32_f16(a[mt], b[nf], mac[mt+4][nf], 0,0,0);
            }
        }
        __syncthreads();   // all waves done reading xf

        if (layer < 5){
            float bias[4];
            #pragma unroll
            for (int nf = 0; nf < 4; ++nf) bias[nf] = bs[layer*256 + ncb + 16*nf + lan15];
            #pragma unroll
            for (int mt = 0; mt < 8; ++mt){
                #pragma unroll
                for (int nf = 0; nf < 4; ++nf){
                    const int n = ncb + 16*nf + lan15;
                    #pragma unroll
                    for (int r = 0; r < 4; ++r){
                        int row = 16*mt + 4*lq + r;   // C/D: col=lane&15, row=(lane>>4)*4+reg
                        xf[XIDX(row, n)] = (half_t)tanh_fast(mac[mt][nf][r] + bias[nf]);
                    }
                }
            }
            __syncthreads();
        } else {
            float bias[4], w[4];
            #pragma unroll
            for (int nf = 0; nf < 4; ++nf){
                const int n = ncb + 16*nf + lan15;
                bias[nf] = bs[5*256 + n];
                w[nf]    = Wout[n];
            }
            float part = 0.f;
            #pragma unroll
            for (int mt = 0; mt < 8; ++mt)
                #pragma unroll
                for (int nf = 0; nf < 4; ++nf)
                    #pragma unroll
                    for (int r = 0; r < 4; ++r)
                        part = fmaf(tanh_fast(mac[mt][nf][r] + bias[nf]), w[nf], part);
            #pragma unroll
            for (int s = 1; s < 64; s <<= 1) part += __shfl_xor(part, s);
            if (lane == 0) redbuf[wv] = part;
            __syncthreads();
            if (tid == 0){
                float s = redbuf[0] + redbuf[1] + redbuf[2] + redbuf[3];
                out[bk] = s + 128.0f * bout[0];
            }
        }
    }
}

extern "C" void kernel_launch(void* const* d_in, const int* in_sizes, int n_in,
                              void* d_out, int out_size, void* d_ws, size_t ws_size,
                              hipStream_t stream)
{
    (void)in_sizes; (void)n_in; (void)out_size; (void)d_ws; (void)ws_size;
    const float* ctx  = (const float*)d_in[0];
    const float* Ws   = (const float*)d_in[1];
    const float* bs   = (const float*)d_in[2];
    const float* Wout = (const float*)d_in[3];
    const float* bout = (const float*)d_in[4];
    float* out = (float*)d_out;

    const int smem_bytes = 128*64*4*2 + 128*4 + 128*4 + 128*4 + 4*4;  // 67088 B -> 2 WGs/CU
    hipFuncSetAttribute(reinterpret_cast<const void*>(fused_mlp_som),
                        hipFuncAttributeMaxDynamicSharedMemorySize, smem_bytes);
    fused_mlp_som<<<dim3(4096), dim3(256), smem_bytes, stream>>>(ctx, Ws, bs, Wout, bout, out);
}

// Round 11
// 1382.427 us; speedup vs baseline: 1.5680x; 1.1104x over previous
//
#include <hip/hip_runtime.h>

// B=64,K=64 -> 4096 (b,k) blocks; L=128 rows; D=128; H=256; 6 layers.
// 512-thread WGs, ~65.5 KB LDS -> 2 WGs/CU co-resident = 16 waves/CU:
// spill-free MLP (64 acc/thread, R6 shape) + phase overlap (R10 win) + 2x TLP.
// [128][64] f32 half-tile, float4-chunk addr (dwords), 4-bit XOR swizzle:
#define HID4(r,c4) ((r)*64 + ((((c4) ^ ((r)&15))) << 2))
// fp16 x-buffer [128][256] over the two half-tiles, swizzled on 8-elem (16B) chunks:
#define XIDX(r,c)  ((r)*256 + (((((c)>>3) ^ ((r)&7))) << 3) + ((c)&7))

typedef _Float16 half_t;
typedef __attribute__((ext_vector_type(8))) _Float16 f16x8;
typedef __attribute__((ext_vector_type(4))) float f32x4;

__device__ __forceinline__ float tanh_fast(float x){
    float e = __expf(2.0f * x);
    return 1.0f - 2.0f / (e + 1.0f);
}

// 8 fp32 -> f16x8 (RNE)
__device__ __forceinline__ f16x8 cvt8(float4 a, float4 b){
    f16x8 r;
    r[0]=(half_t)a.x; r[1]=(half_t)a.y; r[2]=(half_t)a.z; r[3]=(half_t)a.w;
    r[4]=(half_t)b.x; r[5]=(half_t)b.y; r[6]=(half_t)b.z; r[7]=(half_t)b.w;
    return r;
}

__global__ __launch_bounds__(512, 4)   // 4 waves/EU min -> <=128-reg cap so 2 WGs/CU co-reside
void fused_mlp_som(const float* __restrict__ ctx_in,   // (4096, 2, 128, 128) f32
                   const float* __restrict__ Ws,       // (6,256,256)
                   const float* __restrict__ bs,       // (6,256)
                   const float* __restrict__ Wout,     // (256)
                   const float* __restrict__ bout,     // (1)
                   float* __restrict__ out)            // (4096)
{
    extern __shared__ char smem[];
    float* S0     = (float*)smem;                 // [128][64] ctx k-half (32 KB)
    float* S1     = S0 + 128*64;                  // [128][64] ent k-half (32 KB)
    float* inv_cn = S1 + 128*64;                  // [128]
    float* inv_en = inv_cn + 128;                 // [128]
    int*   idxm   = (int*)(inv_en + 128);         // [128]
    float* redbuf = (float*)(idxm + 128);         // [8]
    half_t* xf    = (half_t*)smem;                // [128][256] fp16 over S0+S1, live after sim

    const int tid  = threadIdx.x;
    const int lane = tid & 63;
    const int bk   = blockIdx.x;

    const float*  gctx = ctx_in + (size_t)bk * 32768;
    const float*  gent = gctx + 16384;
    const float4* gc4  = (const float4*)gctx;     // [128][32] float4
    const float4* ge4  = (const float4*)gent;

    // norms: tid<256 -> ctx row chains, tid>=256 -> ent; (hf, nr) as canonical
    const int isEnt = tid >> 8;
    const int hf    = tid & 1;
    const int nr    = (tid >> 1) & 127;
    float ns = 0.f;

    // sim: thread (ti,tj): rows 8ti..8ti+7, cols {tj,+32,+64,+96}
    const int ti = tid >> 5;
    const int tj = tid & 31;
    const int l0 = ti * 8;
    float acc[8][4];
    #pragma unroll
    for (int i = 0; i < 8; ++i)
        #pragma unroll
        for (int j = 0; j < 4; ++j) acc[i][j] = 0.f;

    #pragma unroll 1
    for (int h = 0; h < 2; ++h){
        if (h) __syncthreads();          // all phase-0 readers done before restage
        // ---- stage k-half h: ctx cols 64h.. -> S0, ent -> S1 ----
        #pragma unroll
        for (int it = 0; it < 4; ++it){
            int fi = tid + 512*it;       // 0..2047 over 128x16 chunks
            int r  = fi >> 4;
            int c4 = fi & 15;
            *(float4*)&S0[HID4(r,c4)] = gc4[r*32 + 16*h + c4];
            *(float4*)&S1[HID4(r,c4)] = ge4[r*32 + 16*h + c4];
        }
        __syncthreads();
        // ---- norm partial for this half (canonical 16-chunk chain) ----
        if (hf == h){
            const float* T = isEnt ? S1 : S0;
            #pragma unroll
            for (int u = 0; u < 16; ++u){
                float4 v = *(const float4*)&T[HID4(nr, u)];
                ns = fmaf(v.x, v.x, ns); ns = fmaf(v.y, v.y, ns);
                ns = fmaf(v.z, v.z, ns); ns = fmaf(v.w, v.w, ns);
            }
        }
        // ---- sim accumulate kc = 16h .. 16h+15 (canonical chain order) ----
        for (int kk = 0; kk < 16; ++kk){
            float4 e0 = *(const float4*)&S1[HID4(tj     , kk)];
            float4 e1 = *(const float4*)&S1[HID4(tj + 32, kk)];
            float4 e2 = *(const float4*)&S1[HID4(tj + 64, kk)];
            float4 e3 = *(const float4*)&S1[HID4(tj + 96, kk)];
            #pragma unroll
            for (int i = 0; i < 8; ++i){
                float4 a = *(const float4*)&S0[HID4(l0+i, kk)];
                acc[i][0] = fmaf(a.x,e0.x,acc[i][0]); acc[i][0] = fmaf(a.y,e0.y,acc[i][0]);
                acc[i][0] = fmaf(a.z,e0.z,acc[i][0]); acc[i][0] = fmaf(a.w,e0.w,acc[i][0]);
                acc[i][1] = fmaf(a.x,e1.x,acc[i][1]); acc[i][1] = fmaf(a.y,e1.y,acc[i][1]);
                acc[i][1] = fmaf(a.z,e1.z,acc[i][1]); acc[i][1] = fmaf(a.w,e1.w,acc[i][1]);
                acc[i][2] = fmaf(a.x,e2.x,acc[i][2]); acc[i][2] = fmaf(a.y,e2.y,acc[i][2]);
                acc[i][2] = fmaf(a.z,e2.z,acc[i][2]); acc[i][2] = fmaf(a.w,e2.w,acc[i][2]);
                acc[i][3] = fmaf(a.x,e3.x,acc[i][3]); acc[i][3] = fmaf(a.y,e3.y,acc[i][3]);
                acc[i][3] = fmaf(a.z,e3.z,acc[i][3]); acc[i][3] = fmaf(a.w,e3.w,acc[i][3]);
            }
        }
    }

    // ---- combine norm halves, publish ----
    ns += __shfl_xor(ns, 1);
    if (hf == 0){
        float inv = 1.0f / sqrtf(ns);
        if (isEnt) inv_en[nr] = inv; else inv_cn[nr] = inv;
    }
    __syncthreads();

    // ---- argmax (canonical compare + butterfly) ----
    #pragma unroll
    for (int i = 0; i < 8; ++i){
        float best = -1e38f; int bi = 0;
        #pragma unroll
        for (int j = 0; j < 4; ++j){
            int m = tj + 32*j;
            float v = acc[i][j] * inv_en[m];
            if (v > best || (v == best && m < bi)){ best = v; bi = m; }
        }
        #pragma unroll
        for (int s = 1; s < 32; s <<= 1){
            float ov = __shfl_xor(best, s);
            int   oi = __shfl_xor(bi,   s);
            if (ov > best || (ov == best && oi < bi)){ best = ov; bi = oi; }
        }
        if (tj == 0) idxm[l0 + i] = bi;
    }
    __syncthreads();

    // ---- x0 = [ctx_n | ent_n[idx]] fp16 over S0+S1, from GLOBAL (L2-hot), f16x8 writes ----
    {
        const int l = tid >> 2;          // 0..127
        const int q = tid & 3;           // 0,1: ctx col-halves; 2,3: ent col-halves
        const float4* src;
        float sc;
        int c0;
        if (q < 2){ src = (const float4*)(gctx + l*128 + 64*q);  sc = inv_cn[l]; c0 = 64*q; }
        else { int mi = idxm[l]; src = (const float4*)(gent + mi*128 + 64*(q-2)); sc = inv_en[mi]; c0 = 128 + 64*(q-2); }
        #pragma unroll
        for (int u = 0; u < 8; ++u){
            float4 va = src[2*u];
            float4 vb = src[2*u+1];
            f16x8 hv;
            hv[0]=(half_t)(va.x*sc); hv[1]=(half_t)(va.y*sc); hv[2]=(half_t)(va.z*sc); hv[3]=(half_t)(va.w*sc);
            hv[4]=(half_t)(vb.x*sc); hv[5]=(half_t)(vb.y*sc); hv[6]=(half_t)(vb.z*sc); hv[7]=(half_t)(vb.w*sc);
            int c = c0 + 8*u;            // chunk-aligned
            *(f16x8*)&xf[l*256 + ((((c>>3) ^ (l&7))) << 3)] = hv;
        }
    }
    __syncthreads();

    // ---- 6-layer MLP: fp16 single-product MFMA, 8 waves N-split-8 (R6 shape, 64 acc) ----
    // wave wv owns cols [32wv, 32wv+32); all 128 rows via two a[4] batches.
    const int wv    = tid >> 6;              // 0..7
    const int lan15 = lane & 15;
    const int lq    = lane >> 4;
    const int n0    = 32*wv + lan15;
    const int n1    = n0 + 16;
    const int bno0  = n0 * 256;
    const int bno1  = n1 * 256;
    const int kb    = 8*lq;
    const int aBase = lan15*256;             // + mt*4096 + aoff

    #pragma unroll 1
    for (int layer = 0; layer < 6; ++layer){
        const float* WsL = Ws + layer*65536;

        f32x4 mac[8][2];
        #pragma unroll
        for (int mt = 0; mt < 8; ++mt){
            mac[mt][0] = (f32x4){0.f,0.f,0.f,0.f};
            mac[mt][1] = (f32x4){0.f,0.f,0.f,0.f};
        }

        #pragma unroll 1
        for (int ks = 0; ks < 8; ++ks){
            const int aoff = (((4*ks + lq) ^ (lan15 & 7)) << 3);
            // W frags: fp32 from L2 (hot), cvt inline; latency covered by 16 waves/CU
            f16x8 b0, b1;
            {
                const int kk = 32*ks + kb;
                float4 qa = *(const float4*)&WsL[bno0 + kk];
                float4 qb = *(const float4*)&WsL[bno0 + kk + 4];
                b0 = cvt8(qa, qb);
                float4 qc = *(const float4*)&WsL[bno1 + kk];
                float4 qd = *(const float4*)&WsL[bno1 + kk + 4];
                b1 = cvt8(qc, qd);
            }
            // batch 1: rows 0..63
            {
                f16x8 a[4];
                #pragma unroll
                for (int mt = 0; mt < 4; ++mt)
                    a[mt] = *(const f16x8*)&xf[aBase + mt*4096 + aoff];
                #pragma unroll
                for (int mt = 0; mt < 4; ++mt){
                    mac[mt][0] = __builtin_amdgcn_mfma_f32_16x16x32_f16(a[mt], b0, mac[mt][0], 0,0,0);
                    mac[mt][1] = __builtin_amdgcn_mfma_f32_16x16x32_f16(a[mt], b1, mac[mt][1], 0,0,0);
                }
            }
            // batch 2: rows 64..127
            {
                f16x8 a[4];
                #pragma unroll
                for (int mt = 0; mt < 4; ++mt)
                    a[mt] = *(const f16x8*)&xf[aBase + (mt+4)*4096 + aoff];
                #pragma unroll
                for (int mt = 0; mt < 4; ++mt){
                    mac[mt+4][0] = __builtin_amdgcn_mfma_f32_16x16x32_f16(a[mt], b0, mac[mt+4][0], 0,0,0);
                    mac[mt+4][1] = __builtin_amdgcn_mfma_f32_16x16x32_f16(a[mt], b1, mac[mt+4][1], 0,0,0);
                }
            }
        }
        __syncthreads();   // all waves done reading xf

        if (layer < 5){
            float bias0 = bs[layer*256 + n0];
            float bias1 = bs[layer*256 + n1];
            #pragma unroll
            for (int mt = 0; mt < 8; ++mt){
                #pragma unroll
                for (int r = 0; r < 4; ++r){
                    int row = 16*mt + 4*lq + r;      // C/D: col=lane&15, row=(lane>>4)*4+reg
                    xf[XIDX(row, n0)] = (half_t)tanh_fast(mac[mt][0][r] + bias0);
                    xf[XIDX(row, n1)] = (half_t)tanh_fast(mac[mt][1][r] + bias1);
                }
            }
            __syncthreads();
        } else {
            float bias0 = bs[5*256 + n0];
            float bias1 = bs[5*256 + n1];
            float w0 = Wout[n0];
            float w1 = Wout[n1];
            float part = 0.f;
            #pragma unroll
            for (int mt = 0; mt < 8; ++mt){
                #pragma unroll
                for (int r = 0; r < 4; ++r){
                    part = fmaf(tanh_fast(mac[mt][0][r] + bias0), w0, part);
                    part = fmaf(tanh_fast(mac[mt][1][r] + bias1), w1, part);
                }
            }
            #pragma unroll
            for (int s = 1; s < 64; s <<= 1) part += __shfl_xor(part, s);
            if (lane == 0) redbuf[wv] = part;
            __syncthreads();
            if (tid == 0){
                float s = 0.f;
                #pragma unroll
                for (int i = 0; i < 8; ++i) s += redbuf[i];
                out[bk] = s + 128.0f * bout[0];
            }
        }
    }
}

extern "C" void kernel_launch(void* const* d_in, const int* in_sizes, int n_in,
                              void* d_out, int out_size, void* d_ws, size_t ws_size,
                              hipStream_t stream)
{
    (void)in_sizes; (void)n_in; (void)out_size; (void)d_ws; (void)ws_size;
    const float* ctx  = (const float*)d_in[0];
    const float* Ws   = (const float*)d_in[1];
    const float* bs   = (const float*)d_in[2];
    const float* Wout = (const float*)d_in[3];
    const float* bout = (const float*)d_in[4];
    float* out = (float*)d_out;

    const int smem_bytes = 128*64*4*2 + 128*4 + 128*4 + 128*4 + 8*4;  // 67104 B -> 2 WGs/CU
    hipFuncSetAttribute(reinterpret_cast<const void*>(fused_mlp_som),
                        hipFuncAttributeMaxDynamicSharedMemorySize, smem_bytes);
    fused_mlp_som<<<dim3(4096), dim3(512), smem_bytes, stream>>>(ctx, Ws, bs, Wout, bout, out);
}